// Round 1
// baseline (128.084 us; speedup 1.0000x reference)
//
#include <hip/hip_runtime.h>
#include <math.h>

#define NFOUR 512
#define NSEG 16
#define SEG 64
#define SLEN 1024
#define BB 32
#define MU_F 10.0f
// -MU*T*(2*pi)^(D-1) = -100 * (2*pi)^2
#define LL2_F (-3947.8417604357435f)

__global__ __launch_bounds__(64) void k_mlp(
    const float* __restrict__ noise, const float* __restrict__ W1,
    const float* __restrict__ b1, const float* __restrict__ W2,
    const float* __restrict__ b2, const float* __restrict__ Wm,
    float* __restrict__ wsw)
{
    int n = blockIdx.x;
    int lane = threadIdx.x;
    __shared__ float nz[64];
    __shared__ float h1[100];
    nz[lane] = noise[n * 64 + lane];
    __syncthreads();
    for (int j = lane; j < 100; j += 64) {
        float acc = b1[j];
        #pragma unroll
        for (int k = 0; k < 64; ++k) acc += nz[k] * W1[k * 100 + j];
        h1[j] = tanhf(acc);
    }
    __syncthreads();
    float pd0 = 0.f, pd1 = 0.f, pd2 = 0.f;
    #pragma unroll
    for (int ii = 0; ii < 4; ++ii) {
        int f = lane + ii * 64;
        float acc = b2[f];
        for (int k = 0; k < 100; ++k) acc += h1[k] * W2[k * 256 + f];
        float h2 = tanhf(acc);
        pd0 += h2 * Wm[f * 3 + 0];
        pd1 += h2 * Wm[f * 3 + 1];
        pd2 += h2 * Wm[f * 3 + 2];
    }
    #pragma unroll
    for (int off = 32; off; off >>= 1) {
        pd0 += __shfl_xor(pd0, off);
        pd1 += __shfl_xor(pd1, off);
        pd2 += __shfl_xor(pd2, off);
    }
    if (lane == 0) {
        wsw[n] = pd0;
        wsw[NFOUR + n] = pd1;
        wsw[2 * NFOUR + n] = pd2;
    }
}

__global__ __launch_bounds__(512) void k_seg(
    const float* __restrict__ X, const float* __restrict__ wsw,
    float* __restrict__ segC, float* __restrict__ segS)
{
    int b = blockIdx.x / NSEG, g = blockIdx.x % NSEG;
    int n = threadIdx.x;
    __shared__ float xs[SEG * 3];
    if (n < SEG * 3) xs[n] = X[(b * SLEN + g * SEG) * 3 + n];
    __syncthreads();
    float w0 = wsw[n], w1 = wsw[NFOUR + n], w2 = wsw[2 * NFOUR + n];
    float cA = 0.f, sA = 0.f;
    for (int i = 0; i < SEG; ++i) {
        float th = xs[i * 3] * w0 + xs[i * 3 + 1] * w1 + xs[i * 3 + 2] * w2;
        float sn, cs;
        __sincosf(th, &sn, &cs);
        cA += cs;
        sA += sn;
    }
    segC[(b * NSEG + g) * NFOUR + n] = cA;
    segS[(b * NSEG + g) * NFOUR + n] = sA;
}

__global__ __launch_bounds__(512) void k_main(
    const float* __restrict__ X, const float* __restrict__ wsw,
    const float* __restrict__ segC, const float* __restrict__ segS,
    const float* __restrict__ alpha, float* __restrict__ out)
{
    int b = blockIdx.x / NSEG, g = blockIdx.x % NSEG;
    int n = threadIdx.x;
    int lane = n & 63, wv = n >> 6;
    __shared__ float xs[SEG * 3];
    __shared__ float wpart[8][SEG];
    if (n < SEG * 3) xs[n] = X[(b * SLEN + g * SEG) * 3 + n];
    float cC = 0.f, sS = 0.f;
    for (int gp = 0; gp < g; ++gp) {
        cC += segC[(b * NSEG + gp) * NFOUR + n];
        sS += segS[(b * NSEG + gp) * NFOUR + n];
    }
    __syncthreads();
    float w0 = wsw[n], w1 = wsw[NFOUR + n], w2 = wsw[2 * NFOUR + n];
    for (int i = 0; i < SEG; ++i) {
        float th = xs[i * 3] * w0 + xs[i * 3 + 1] * w1 + xs[i * 3 + 2] * w2;
        float sn, cs;
        __sincosf(th, &sn, &cs);
        float contrib = cs * cC + sn * sS;   // exclusive prefix: before adding own
        contrib += __shfl_xor(contrib, 32);
        contrib += __shfl_xor(contrib, 16);
        contrib += __shfl_xor(contrib, 8);
        contrib += __shfl_xor(contrib, 4);
        contrib += __shfl_xor(contrib, 2);
        contrib += __shfl_xor(contrib, 1);
        if (lane == 0) wpart[wv][i] = contrib;
        cC += cs;
        sS += sn;
    }
    __syncthreads();
    if (n < SEG) {
        float a0 = alpha[0];
        float tot = 0.f;
        #pragma unroll
        for (int w = 0; w < 8; ++w) tot += wpart[w][n];
        float lam = a0 * tot * (1.0f / (float)NFOUR) + MU_F;
        int s = g * SEG + n;
        out[b * SLEN + s] = lam;
        float m = (xs[n * 3] > 0.f) ? 1.f : 0.f;
        out[BB * SLEN + b * (SLEN + 1) + s] = __logf(lam) * m + LL2_F;
    }
    // tail column loglik[:, S] = LL2 (32 values), done once by block g==0
    if (g == 0 && n >= 64 && n < 64 + BB) {
        out[BB * SLEN + (n - 64) * (SLEN + 1) + SLEN] = LL2_F;
    }
}

extern "C" void kernel_launch(void* const* d_in, const int* in_sizes, int n_in,
                              void* d_out, int out_size, void* d_ws, size_t ws_size,
                              hipStream_t stream) {
    const float* X     = (const float*)d_in[0];
    const float* noise = (const float*)d_in[1];
    const float* W1    = (const float*)d_in[2];
    const float* b1    = (const float*)d_in[3];
    const float* W2    = (const float*)d_in[4];
    const float* b2    = (const float*)d_in[5];
    const float* Wm    = (const float*)d_in[6];
    const float* alpha = (const float*)d_in[7];
    float* out = (float*)d_out;
    float* ws  = (float*)d_ws;

    float* wsw  = ws;                       // 3*512 floats (Womg, SoA)
    float* segC = ws + 2048;                // B*NSEG*NF floats
    float* segS = segC + BB * NSEG * NFOUR; // B*NSEG*NF floats

    k_mlp<<<NFOUR, 64, 0, stream>>>(noise, W1, b1, W2, b2, Wm, wsw);
    k_seg<<<BB * NSEG, 512, 0, stream>>>(X, wsw, segC, segS);
    k_main<<<BB * NSEG, 512, 0, stream>>>(X, wsw, segC, segS, alpha, out);
}

// Round 2
// 98.267 us; speedup vs baseline: 1.3034x; 1.3034x over previous
//
#include <hip/hip_runtime.h>
#include <math.h>

#define NFOUR 512
#define NSEG 16
#define SEG 64
#define SLEN 1024
#define BB 32
#define CH 16
#define MU_F 10.0f
// -MU*T*(2*pi)^(D-1) = -100 * (2*pi)^2
#define LL2_F (-3947.8417604357435f)

__global__ __launch_bounds__(256) void k_mlp(
    const float* __restrict__ noise, const float* __restrict__ W1,
    const float* __restrict__ b1, const float* __restrict__ W2,
    const float* __restrict__ b2, const float* __restrict__ Wm,
    float* __restrict__ wsw)
{
    int n = blockIdx.x;
    int t = threadIdx.x;
    __shared__ float nz[64];
    __shared__ float h1[100];
    __shared__ float red[3][4];
    if (t < 64) nz[t] = noise[n * 64 + t];
    __syncthreads();
    if (t < 100) {
        float acc = b1[t];
        #pragma unroll
        for (int k = 0; k < 64; ++k) acc += nz[k] * W1[k * 100 + t];
        h1[t] = tanhf(acc);
    }
    __syncthreads();
    float acc = b2[t];
    #pragma unroll 4
    for (int k = 0; k < 100; ++k) acc += h1[k] * W2[k * 256 + t];
    float h2 = tanhf(acc);
    float pd0 = h2 * Wm[t * 3 + 0];
    float pd1 = h2 * Wm[t * 3 + 1];
    float pd2 = h2 * Wm[t * 3 + 2];
    #pragma unroll
    for (int off = 32; off; off >>= 1) {
        pd0 += __shfl_xor(pd0, off);
        pd1 += __shfl_xor(pd1, off);
        pd2 += __shfl_xor(pd2, off);
    }
    if ((t & 63) == 0) {
        red[0][t >> 6] = pd0;
        red[1][t >> 6] = pd1;
        red[2][t >> 6] = pd2;
    }
    __syncthreads();
    if (t == 0) {
        wsw[n]             = red[0][0] + red[0][1] + red[0][2] + red[0][3];
        wsw[NFOUR + n]     = red[1][0] + red[1][1] + red[1][2] + red[1][3];
        wsw[2 * NFOUR + n] = red[2][0] + red[2][1] + red[2][2] + red[2][3];
    }
}

__global__ __launch_bounds__(512) void k_seg(
    const float* __restrict__ X, const float* __restrict__ wsw,
    float* __restrict__ segC, float* __restrict__ segS)
{
    int b = blockIdx.x / NSEG, g = blockIdx.x % NSEG;
    int n = threadIdx.x;
    __shared__ float xs[SEG * 3];
    if (n < SEG * 3) xs[n] = X[(b * SLEN + g * SEG) * 3 + n];
    __syncthreads();
    float w0 = wsw[n], w1 = wsw[NFOUR + n], w2 = wsw[2 * NFOUR + n];
    float cA = 0.f, sA = 0.f;
    #pragma unroll 8
    for (int i = 0; i < SEG; ++i) {
        float th = xs[i * 3] * w0 + xs[i * 3 + 1] * w1 + xs[i * 3 + 2] * w2;
        float sn, cs;
        __sincosf(th, &sn, &cs);
        cA += cs;
        sA += sn;
    }
    segC[(b * NSEG + g) * NFOUR + n] = cA;
    segS[(b * NSEG + g) * NFOUR + n] = sA;
}

__global__ __launch_bounds__(512) void k_main(
    const float* __restrict__ X, const float* __restrict__ wsw,
    const float* __restrict__ segC, const float* __restrict__ segS,
    const float* __restrict__ alpha, float* __restrict__ out)
{
    int b = blockIdx.x / NSEG, g = blockIdx.x % NSEG;
    int n = threadIdx.x;
    __shared__ float xs[SEG * 3];
    __shared__ float buf[CH][NFOUR];
    if (n < SEG * 3) xs[n] = X[(b * SLEN + g * SEG) * 3 + n];
    float cC = 0.f, sS = 0.f;
    for (int gp = 0; gp < g; ++gp) {
        cC += segC[(b * NSEG + gp) * NFOUR + n];
        sS += segS[(b * NSEG + gp) * NFOUR + n];
    }
    float w0 = wsw[n], w1 = wsw[NFOUR + n], w2 = wsw[2 * NFOUR + n];
    float a0 = alpha[0];
    __syncthreads();
    int r = n >> 5, c = n & 31;
    for (int ch = 0; ch < 4; ++ch) {
        #pragma unroll
        for (int i = 0; i < CH; ++i) {
            int s = ch * CH + i;
            float th = xs[s * 3] * w0 + xs[s * 3 + 1] * w1 + xs[s * 3 + 2] * w2;
            float sn, cs;
            __sincosf(th, &sn, &cs);
            buf[i][n] = cs * cC + sn * sS;   // exclusive prefix contribution
            cC += cs;
            sS += sn;
        }
        __syncthreads();
        // transpose-reduce: 32 threads per row, each sums 16 floats (4x b128)
        float4 v0 = *(const float4*)&buf[r][c * 4 + 0];
        float4 v1 = *(const float4*)&buf[r][c * 4 + 128];
        float4 v2 = *(const float4*)&buf[r][c * 4 + 256];
        float4 v3 = *(const float4*)&buf[r][c * 4 + 384];
        float acc = (v0.x + v0.y + v0.z + v0.w) + (v1.x + v1.y + v1.z + v1.w)
                  + (v2.x + v2.y + v2.z + v2.w) + (v3.x + v3.y + v3.z + v3.w);
        acc += __shfl_xor(acc, 16);
        acc += __shfl_xor(acc, 8);
        acc += __shfl_xor(acc, 4);
        acc += __shfl_xor(acc, 2);
        acc += __shfl_xor(acc, 1);
        if (c == 0) {
            int s = ch * CH + r;
            float lam = a0 * acc * (1.0f / (float)NFOUR) + MU_F;
            int sg = g * SEG + s;
            out[b * SLEN + sg] = lam;
            float m = (xs[s * 3] > 0.f) ? 1.f : 0.f;
            out[BB * SLEN + b * (SLEN + 1) + sg] = __logf(lam) * m + LL2_F;
        }
        __syncthreads();
    }
    // tail column loglik[:, S] = LL2 (32 values), done once by block g==0
    if (g == 0 && n >= 64 && n < 64 + BB) {
        out[BB * SLEN + (n - 64) * (SLEN + 1) + SLEN] = LL2_F;
    }
}

extern "C" void kernel_launch(void* const* d_in, const int* in_sizes, int n_in,
                              void* d_out, int out_size, void* d_ws, size_t ws_size,
                              hipStream_t stream) {
    const float* X     = (const float*)d_in[0];
    const float* noise = (const float*)d_in[1];
    const float* W1    = (const float*)d_in[2];
    const float* b1    = (const float*)d_in[3];
    const float* W2    = (const float*)d_in[4];
    const float* b2    = (const float*)d_in[5];
    const float* Wm    = (const float*)d_in[6];
    const float* alpha = (const float*)d_in[7];
    float* out = (float*)d_out;
    float* ws  = (float*)d_ws;

    float* wsw  = ws;                       // 3*512 floats (Womg, SoA)
    float* segC = ws + 2048;                // B*NSEG*NF floats
    float* segS = segC + BB * NSEG * NFOUR; // B*NSEG*NF floats

    k_mlp<<<NFOUR, 256, 0, stream>>>(noise, W1, b1, W2, b2, Wm, wsw);
    k_seg<<<BB * NSEG, 512, 0, stream>>>(X, wsw, segC, segS);
    k_main<<<BB * NSEG, 512, 0, stream>>>(X, wsw, segC, segS, alpha, out);
}